// Round 10
// baseline (120.674 us; speedup 1.0000x reference)
//
#include <hip/hip_runtime.h>
#include <hip/hip_fp16.h>
#include <math.h>

#define BN 8192
#define NT 512
#define NW (NT / 64)
#define NGRP 4                 // 4 float4-groups/thread: 4*512*4 = 8192
#define INV_TAU (1.0f / 0.07f)
#define COFF 40.0f             // fixed softmax offset (replaces row max; exact math)
#define K2F 20.609929156f      // INV_TAU * log2(e)
#define C2F 57.707801636f      // COFF   * log2(e)
#define NPB 32                 // prep blocks
#define COL_BLKS 256
#define CPB (BN / COL_BLKS)    // 32 rows/cols per col-block

// Plain-store workspace: no zero-init required (prep resets `done` every call).
struct Header {
  int   part_P[NPB];
  int   part_RN[NPB];
  float part_A[NPB];
  float part_prior[NPB];
  float w_inf, w_pu, w_prior;
  int   done;                  // col-block completion counter
  float pu_part[COL_BLKS];
  float ii_part[COL_BLKS];     // ir + ic partials
};
// ws offsets (bytes): header @0 | code @4096 (32KB) | loss_pu @40960 (32KB) | ir @73728 (32KB)

// ---------------- prep (32 blocks): per-block partial stats + packed selector code --------
// code[j] = half2 { v, q } : v = alpha (pos) | -beta (rn) | 0 ; q = 1 if unlabeled else 0
__global__ void prep_kernel(const int* __restrict__ labels, const float* __restrict__ alphas,
                            const float* __restrict__ betas, const float* __restrict__ pia,
                            const float* __restrict__ pie, const int* __restrict__ epoch_p,
                            Header* __restrict__ hd, __half2* __restrict__ code) {
  const int j = blockIdx.x * 256 + threadIdx.x;   // 32 * 256 = 8192
  const int l = labels[j];
  const bool isp = (l == 1), isrn = (l == -1);
  const float v = isp ? alphas[j] : (isrn ? -betas[j] : 0.f);
  const __half vh = __float2half(v);
  code[j] = __halves2half2(vh, __float2half((!isp && !isrn) ? 1.f : 0.f));
  int p = isp ? 1 : 0, rn = isrn ? 1 : 0;
  float a = isp ? __half2float(vh) : 0.f;         // A_tot from the SAME rounded alphas
  const float d = pia[j] - pie[j];
  float pr = d * d;
#pragma unroll
  for (int off = 32; off > 0; off >>= 1) {
    p  += __shfl_xor(p, off);
    rn += __shfl_xor(rn, off);
    a  += __shfl_xor(a, off);
    pr += __shfl_xor(pr, off);
  }
  __shared__ int sp_[4], srn_[4];
  __shared__ float sa_[4], spr_[4];
  const int wid = threadIdx.x >> 6;
  if ((threadIdx.x & 63) == 0) { sp_[wid] = p; srn_[wid] = rn; sa_[wid] = a; spr_[wid] = pr; }
  __syncthreads();
  if (threadIdx.x == 0) {
    int P = 0, RN = 0; float A = 0.f, PR = 0.f;
#pragma unroll
    for (int w = 0; w < 4; ++w) { P += sp_[w]; RN += srn_[w]; A += sa_[w]; PR += spr_[w]; }
    hd->part_P[blockIdx.x] = P;
    hd->part_RN[blockIdx.x] = RN;
    hd->part_A[blockIdx.x] = A;
    hd->part_prior[blockIdx.x] = PR;
    if (blockIdx.x == 0) {
      const int ep = epoch_p[0];
      float w_inf, w_pu, w_prior;
      if (ep < 5) { w_inf = 1.f; w_pu = 0.f; w_prior = 0.f; }
      else {
        const float puw = (ep >= 15) ? 1.f : (float)(ep - 5) / 10.f;
        w_inf = 1.f - puw; w_pu = puw; w_prior = (ep >= 15) ? 1.f : 0.f;
      }
      hd->w_inf = w_inf; hd->w_pu = w_pu; hd->w_prior = w_prior;
      hd->done = 0;                       // reset last-block counter every call
    }
  }
}

// ---------------- per-row PU loss + gated infonce row LSE ----------------
// 12 float4 loads issued interleaved, PINNED above compute via sched_barrier(0)
// so the scheduler cannot sink them (observed VGPR=32 = sunk loads in r9).
__launch_bounds__(NT, 4)
__global__ void row_kernel(const float* __restrict__ sim, const float* __restrict__ pw,
                           const __half2* __restrict__ code, const float* __restrict__ pia,
                           const Header* __restrict__ hd, float* __restrict__ loss_pu,
                           float* __restrict__ ir) {
  const int row = blockIdx.x;
  const float w_pu = hd->w_pu, w_inf = hd->w_inf;
  if (w_pu == 0.0f && w_inf == 0.0f) return;
  const bool do_pu = (w_pu != 0.0f);

  const float4* __restrict__ sim4 = (const float4*)(sim + (size_t)row * BN);
  const float4* __restrict__ cd4  = (const float4*)code;
  const float4* __restrict__ pwp  = do_pu ? (const float4*)(pw + (size_t)row * BN) : sim4;

  // ---- interleaved load issue: group it ready after load 3*it+2 ----
  float4 s4[NGRP], w4[NGRP], c4[NGRP];
#pragma unroll
  for (int it = 0; it < NGRP; ++it) {
    const int v = threadIdx.x + it * NT;
    s4[it] = sim4[v];
    w4[it] = pwp[v];
    c4[it] = cd4[v];
  }
  __builtin_amdgcn_sched_barrier(0);   // pin all 12 loads above compute

  float se = 0.f, sp = 0.f, srn = 0.f, su = 0.f, sas = 0.f;
#pragma unroll
  for (int it = 0; it < NGRP; ++it) {
    const float sv[4] = {s4[it].x, s4[it].y, s4[it].z, s4[it].w};
    const float wv[4] = {w4[it].x, w4[it].y, w4[it].z, w4[it].w};
    const float cf[4] = {c4[it].x, c4[it].y, c4[it].z, c4[it].w};
#pragma unroll
    for (int c = 0; c < 4; ++c) {
      const __half2 h = __builtin_bit_cast(__half2, cf[c]);
      const float2 f = __half22float2(h);     // f.x = v (+alpha/-beta/0), f.y = q (1 if u)
      const float s = sv[c];
      const float ex = exp2f(fmaf(s, K2F, -C2F));   // = exp(s/tau - COFF)
      se += ex;
      const float we = wv[c] * ex;
      sp += (f.x > 0.f) ? ex : 0.f;
      su  = fmaf(f.y, we, su);
      srn = fmaf(fmaxf(-f.x, 0.f), we, srn);
      sas = fmaf(fmaxf(f.x, 0.f), s, sas);
    }
  }

  const int wid = threadIdx.x >> 6;
  const int lane = threadIdx.x & 63;
#pragma unroll
  for (int off = 32; off > 0; off >>= 1) {
    se  += __shfl_xor(se, off);
    sp  += __shfl_xor(sp, off);
    srn += __shfl_xor(srn, off);
    su  += __shfl_xor(su, off);
    sas += __shfl_xor(sas, off);
  }
  __shared__ float red[NW][8];
  if (lane == 0) {
    red[wid][0] = se; red[wid][1] = sp; red[wid][2] = srn;
    red[wid][3] = su; red[wid][4] = sas;
  }
  __syncthreads();

  if (threadIdx.x == 0) {
    double Se = 0.0, Sp = 0.0, Sr = 0.0, Su = 0.0, Sa = 0.0;
#pragma unroll
    for (int w = 0; w < NW; ++w) {
      Se += (double)red[w][0]; Sp += (double)red[w][1]; Sr += (double)red[w][2];
      Su += (double)red[w][3]; Sa += (double)red[w][4];
    }
    // diagonal contributions (self-exclusion in closed form); row is cache-hot
    const float s_rr = sim[(size_t)row * BN + row];
    const float l_rr = s_rr * INV_TAU;
    const float ex_rr_f = exp2f(fmaf(s_rr, K2F, -C2F));  // same fp as loop -> exact cancel
    const double ex_rr = (double)ex_rr_f;
    const float2 fr = __half22float2(code[row]);
    const bool rp = fr.x > 0.f, rrn = fr.x < 0.f, ru = fr.y > 0.5f;
    const float asr = fmaxf(fr.x, 0.f);
    const float rbr = fmaxf(-fr.x, 0.f);

    const double se_ex = fmax(Se - ex_rr, 1e-300);
    const double logZ = (double)COFF + log(se_ex);

    if (do_pu) {
      int P_tot = 0, RN_tot = 0; float A_tot = 0.f;
#pragma unroll
      for (int b = 0; b < NPB; ++b) {
        P_tot += hd->part_P[b]; RN_tot += hd->part_RN[b]; A_tot += hd->part_A[b];
      }
      const float pw_rr = pw[(size_t)row * BN + row];
      const int U_tot = BN - P_tot - RN_tot;
      const int cp  = P_tot  - (rp ? 1 : 0);
      const int crn = RN_tot - (rrn ? 1 : 0);
      const int cu  = U_tot  - (ru ? 1 : 0);
      const double Apos  = (double)A_tot - (double)asr;
      const double SaL   = (double)INV_TAU * Sa - (double)asr * (double)l_rr;
      const double sp_ex = Sp - (rp ? ex_rr : 0.0);
      const double sr_ex = Sr - (double)rbr * (double)pw_rr * ex_rr;
      const double su_ex = Su - (ru ? (double)pw_rr * ex_rr : 0.0);

      const double Lpos = (cp > 0) ? (-(SaL - logZ * Apos) / cp) : 0.0;
      const double Lrn  = (crn > 0) ? ((sr_ex / se_ex) / crn) : 0.0;
      const double EU = (su_ex / se_ex) / (cu > 0 ? cu : 1);
      const double EP = (sp_ex / se_ex) / (cp > 0 ? cp : 1);
      double pi = (double)pia[row];
      pi = pi < 1e-4 ? 1e-4 : (pi > 0.5 ? 0.5 : pi);
      const double deb = (EU - pi * EP) / (1.0 - pi + 1e-8);
      const double Lu = (cu > 0 && cp > 0) ? (deb > 0.0 ? deb : 0.0) : 0.0;
      loss_pu[row] = (float)(Lpos + Lrn + Lu);
    }
    if (w_inf != 0.0f) {
      const double logZf = (double)COFF + log(Se);   // full row LSE (self included)
      ir[row] = (float)(logZf - (double)l_rr);
    }
  }
}

// ---------------- col: infonce column LSE (gated) + slice partials + last-block combine ----
__launch_bounds__(256)
__global__ void col_kernel(const float* __restrict__ sim, Header* __restrict__ hd,
                           const float* __restrict__ loss_pu, const float* __restrict__ ir,
                           float* __restrict__ out) {
  const float w_inf = hd->w_inf, w_pu = hd->w_pu, w_prior = hd->w_prior;
  const int b = blockIdx.x;
  const int t = threadIdx.x;
  const int wid = t >> 6, lane = t & 63;

  // 1) column LSE for this block's 32 columns (only when epoch < PHASE2_END)
  double ic_sum = 0.0;   // accumulated in thread 0
  if (w_inf != 0.0f) {
    __shared__ float red[4][3];
    for (int k = 0; k < CPB; ++k) {
      const int col = b * CPB + k;
      float m = -3.0e38f, se = 0.f, diag = 0.f;
      for (int r = t; r < BN; r += 256) {
        const float l = sim[(size_t)r * BN + col] * INV_TAU;
        if (r == col) diag = l;
        if (l > m) { se *= __expf(m - l); m = l; }
        se += __expf(l - m);
      }
#pragma unroll
      for (int off = 32; off > 0; off >>= 1) {
        const float m2 = __shfl_xor(m, off), se2 = __shfl_xor(se, off);
        diag += __shfl_xor(diag, off);
        const float mn = fmaxf(m, m2);
        se = se * __expf(m - mn) + se2 * __expf(m2 - mn);
        m = mn;
      }
      if (lane == 0) { red[wid][0] = m; red[wid][1] = se; red[wid][2] = diag; }
      __syncthreads();
      if (t == 0) {
        float M = red[0][0], Se = red[0][1], Dg = red[0][2];
        for (int w = 1; w < 4; ++w) {
          const float mn = fmaxf(M, red[w][0]);
          Se = Se * __expf(M - mn) + red[w][1] * __expf(red[w][0] - mn);
          M = mn;
          Dg += red[w][2];
        }
        ic_sum += (double)M + log((double)Se) - (double)Dg;
      }
      __syncthreads();
    }
  }

  // 2) slice partials: rows [b*32, b*32+32) of loss_pu / ir
  float ps = 0.f, is_ = 0.f;
  if (t < CPB) {
    const int r = b * CPB + t;
    if (w_pu  != 0.0f) ps  = loss_pu[r];
    if (w_inf != 0.0f) is_ = ir[r];
  }
  if (t < 64) {
#pragma unroll
    for (int off = 32; off > 0; off >>= 1) {
      ps  += __shfl_xor(ps, off);
      is_ += __shfl_xor(is_, off);
    }
  }
  if (t == 0) {
    hd->pu_part[b] = ps;
    hd->ii_part[b] = is_ + (float)ic_sum;
  }
  __threadfence();
  __shared__ int last;
  if (t == 0) last = (atomicAdd(&hd->done, 1) == COL_BLKS - 1) ? 1 : 0;
  __syncthreads();
  if (!last) return;
  __threadfence();

  // 3) last block: final combine (deterministic regardless of which block is last)
  double pu = (double)hd->pu_part[t];
  double ii = (double)hd->ii_part[t];
  double pr = (t < NPB) ? (double)hd->part_prior[t] : 0.0;
#pragma unroll
  for (int off = 32; off > 0; off >>= 1) {
    pu += __shfl_xor(pu, off);
    ii += __shfl_xor(ii, off);
    pr += __shfl_xor(pr, off);
  }
  __shared__ double red2[4][3];
  if (lane == 0) { red2[wid][0] = pu; red2[wid][1] = ii; red2[wid][2] = pr; }
  __syncthreads();
  if (t == 0) {
    double PU = 0, II = 0, PR = 0;
#pragma unroll
    for (int w = 0; w < 4; ++w) { PU += red2[w][0]; II += red2[w][1]; PR += red2[w][2]; }
    double total = 0.0;
    if (w_pu    != 0.0f) total += (double)w_pu * (PU / (double)BN);
    if (w_inf   != 0.0f) total += (double)w_inf * (II / (2.0 * (double)BN));
    if (w_prior != 0.0f) total += (double)w_prior * 0.1 * (PR / (double)BN);
    out[0] = (float)total;
  }
}

extern "C" void kernel_launch(void* const* d_in, const int* in_sizes, int n_in,
                              void* d_out, int out_size, void* d_ws, size_t ws_size,
                              hipStream_t stream) {
  const float* sim    = (const float*)d_in[0];
  const int*   labels = (const int*)d_in[1];
  const float* alphas = (const float*)d_in[2];
  const float* betas  = (const float*)d_in[3];
  const float* pia    = (const float*)d_in[4];
  const float* pw     = (const float*)d_in[5];
  const float* pie    = (const float*)d_in[6];
  const int*   epoch  = (const int*)d_in[7];
  Header*  hd      = (Header*)d_ws;
  __half2* code    = (__half2*)((char*)d_ws + 4096);
  float*   loss_pu = (float*)((char*)d_ws + 40960);
  float*   ir      = (float*)((char*)d_ws + 73728);
  float*   out     = (float*)d_out;

  hipLaunchKernelGGL(prep_kernel, dim3(NPB), dim3(256), 0, stream,
                     labels, alphas, betas, pia, pie, epoch, hd, code);
  hipLaunchKernelGGL(row_kernel, dim3(BN), dim3(NT), 0, stream,
                     sim, pw, code, pia, hd, loss_pu, ir);
  hipLaunchKernelGGL(col_kernel, dim3(COL_BLKS), dim3(256), 0, stream,
                     sim, hd, loss_pu, ir, out);
}

// Round 11
// 119.252 us; speedup vs baseline: 1.0119x; 1.0119x over previous
//
#include <hip/hip_runtime.h>
#include <hip/hip_fp16.h>
#include <math.h>

#define BN 8192
#define NT 512
#define NW (NT / 64)
#define NGRP 4                 // 4 float4-groups/thread: 4*512*4 = 8192
#define INV_TAU (1.0f / 0.07f)
#define COFF 40.0f             // fixed softmax offset (replaces row max; exact math)
#define K2F 20.609929156f      // INV_TAU * log2(e)
#define C2F 57.707801636f      // COFF   * log2(e)
#define NPB 32                 // prep blocks
#define COL_BLKS 256
#define CPB (BN / COL_BLKS)    // 32 rows/cols per col-block

typedef float f4 __attribute__((ext_vector_type(4)));

// Plain-store workspace: no zero-init required (prep resets `done` every call).
struct Header {
  int   part_P[NPB];
  int   part_RN[NPB];
  float part_A[NPB];
  float part_prior[NPB];
  float w_inf, w_pu, w_prior;
  int   done;                  // col-block completion counter
  float pu_part[COL_BLKS];
  float ii_part[COL_BLKS];     // ir + ic partials
};
// ws offsets (bytes): header @0 | code @4096 (32KB) | loss_pu @40960 (32KB) | ir @73728 (32KB)

// ---------------- prep (32 blocks): per-block partial stats + packed selector code --------
// code[j] = half2 { v, q } : v = alpha (pos) | -beta (rn) | 0 ; q = 1 if unlabeled else 0
__global__ void prep_kernel(const int* __restrict__ labels, const float* __restrict__ alphas,
                            const float* __restrict__ betas, const float* __restrict__ pia,
                            const float* __restrict__ pie, const int* __restrict__ epoch_p,
                            Header* __restrict__ hd, __half2* __restrict__ code) {
  const int j = blockIdx.x * 256 + threadIdx.x;   // 32 * 256 = 8192
  const int l = labels[j];
  const bool isp = (l == 1), isrn = (l == -1);
  const float v = isp ? alphas[j] : (isrn ? -betas[j] : 0.f);
  const __half vh = __float2half(v);
  code[j] = __halves2half2(vh, __float2half((!isp && !isrn) ? 1.f : 0.f));
  int p = isp ? 1 : 0, rn = isrn ? 1 : 0;
  float a = isp ? __half2float(vh) : 0.f;         // A_tot from the SAME rounded alphas
  const float d = pia[j] - pie[j];
  float pr = d * d;
#pragma unroll
  for (int off = 32; off > 0; off >>= 1) {
    p  += __shfl_xor(p, off);
    rn += __shfl_xor(rn, off);
    a  += __shfl_xor(a, off);
    pr += __shfl_xor(pr, off);
  }
  __shared__ int sp_[4], srn_[4];
  __shared__ float sa_[4], spr_[4];
  const int wid = threadIdx.x >> 6;
  if ((threadIdx.x & 63) == 0) { sp_[wid] = p; srn_[wid] = rn; sa_[wid] = a; spr_[wid] = pr; }
  __syncthreads();
  if (threadIdx.x == 0) {
    int P = 0, RN = 0; float A = 0.f, PR = 0.f;
#pragma unroll
    for (int w = 0; w < 4; ++w) { P += sp_[w]; RN += srn_[w]; A += sa_[w]; PR += spr_[w]; }
    hd->part_P[blockIdx.x] = P;
    hd->part_RN[blockIdx.x] = RN;
    hd->part_A[blockIdx.x] = A;
    hd->part_prior[blockIdx.x] = PR;
    if (blockIdx.x == 0) {
      const int ep = epoch_p[0];
      float w_inf, w_pu, w_prior;
      if (ep < 5) { w_inf = 1.f; w_pu = 0.f; w_prior = 0.f; }
      else {
        const float puw = (ep >= 15) ? 1.f : (float)(ep - 5) / 10.f;
        w_inf = 1.f - puw; w_pu = puw; w_prior = (ep >= 15) ? 1.f : 0.f;
      }
      hd->w_inf = w_inf; hd->w_pu = w_pu; hd->w_prior = w_prior;
      hd->done = 0;                       // reset last-block counter every call
    }
  }
}

// ---------------- per-row PU loss + gated infonce row LSE ----------------
// 12 global_load_dwordx4 pinned in flight via inline asm (compiler cannot sink them);
// progressive s_waitcnt vmcnt(9/6/3/0) before each group's compute (AITER pattern).
__launch_bounds__(NT, 4)
__global__ void row_kernel(const float* __restrict__ sim, const float* __restrict__ pw,
                           const __half2* __restrict__ code, const float* __restrict__ pia,
                           const Header* __restrict__ hd, float* __restrict__ loss_pu,
                           float* __restrict__ ir) {
  const int row = blockIdx.x;
  const float w_pu = hd->w_pu, w_inf = hd->w_inf;
  if (w_pu == 0.0f && w_inf == 0.0f) return;
  const bool do_pu = (w_pu != 0.0f);

  const float* __restrict__ srow = sim + (size_t)row * BN;
  const float* __restrict__ wrow = do_pu ? (pw + (size_t)row * BN) : srow;
  const float* __restrict__ crow = (const float*)code;   // 32KB, byte-offsets match srow's

  // ---- issue 12 loads interleaved (s,w,c per group); asm volatile pins them in flight ----
  f4 s4[NGRP], w4[NGRP], c4[NGRP];
  unsigned voff[NGRP];
#pragma unroll
  for (int it = 0; it < NGRP; ++it) voff[it] = (unsigned)(threadIdx.x + it * NT) * 16u;
#pragma unroll
  for (int it = 0; it < NGRP; ++it) {
    asm volatile("global_load_dwordx4 %0, %1, %2" : "=v"(s4[it]) : "v"(voff[it]), "s"(srow));
    asm volatile("global_load_dwordx4 %0, %1, %2" : "=v"(w4[it]) : "v"(voff[it]), "s"(wrow));
    asm volatile("global_load_dwordx4 %0, %1, %2" : "=v"(c4[it]) : "v"(voff[it]), "s"(crow));
  }

  float se = 0.f, sp = 0.f, srn = 0.f, su = 0.f, sas = 0.f;
#pragma unroll
  for (int it = 0; it < NGRP; ++it) {
    // wait until this group's 3 loads (the 3 oldest outstanding) completed;
    // "+v" ties make the consumers data-depend on the post-wait registers.
    switch (it) {
      case 0: asm volatile("s_waitcnt vmcnt(9)" : "+v"(s4[0]), "+v"(w4[0]), "+v"(c4[0])); break;
      case 1: asm volatile("s_waitcnt vmcnt(6)" : "+v"(s4[1]), "+v"(w4[1]), "+v"(c4[1])); break;
      case 2: asm volatile("s_waitcnt vmcnt(3)" : "+v"(s4[2]), "+v"(w4[2]), "+v"(c4[2])); break;
      case 3: asm volatile("s_waitcnt vmcnt(0)" : "+v"(s4[3]), "+v"(w4[3]), "+v"(c4[3])); break;
    }
    __builtin_amdgcn_sched_barrier(0);
    const float sv[4] = {s4[it].x, s4[it].y, s4[it].z, s4[it].w};
    const float wv[4] = {w4[it].x, w4[it].y, w4[it].z, w4[it].w};
    const float cf[4] = {c4[it].x, c4[it].y, c4[it].z, c4[it].w};
#pragma unroll
    for (int c = 0; c < 4; ++c) {
      const __half2 h = __builtin_bit_cast(__half2, cf[c]);
      const float2 f = __half22float2(h);     // f.x = v (+alpha/-beta/0), f.y = q (1 if u)
      const float s = sv[c];
      const float ex = exp2f(fmaf(s, K2F, -C2F));   // = exp(s/tau - COFF)
      se += ex;
      const float we = wv[c] * ex;
      sp += (f.x > 0.f) ? ex : 0.f;
      su  = fmaf(f.y, we, su);
      srn = fmaf(fmaxf(-f.x, 0.f), we, srn);
      sas = fmaf(fmaxf(f.x, 0.f), s, sas);
    }
  }

  const int wid = threadIdx.x >> 6;
  const int lane = threadIdx.x & 63;
#pragma unroll
  for (int off = 32; off > 0; off >>= 1) {
    se  += __shfl_xor(se, off);
    sp  += __shfl_xor(sp, off);
    srn += __shfl_xor(srn, off);
    su  += __shfl_xor(su, off);
    sas += __shfl_xor(sas, off);
  }
  __shared__ float red[NW][8];
  if (lane == 0) {
    red[wid][0] = se; red[wid][1] = sp; red[wid][2] = srn;
    red[wid][3] = su; red[wid][4] = sas;
  }
  __syncthreads();

  if (threadIdx.x == 0) {
    double Se = 0.0, Sp = 0.0, Sr = 0.0, Su = 0.0, Sa = 0.0;
#pragma unroll
    for (int w = 0; w < NW; ++w) {
      Se += (double)red[w][0]; Sp += (double)red[w][1]; Sr += (double)red[w][2];
      Su += (double)red[w][3]; Sa += (double)red[w][4];
    }
    // diagonal contributions (self-exclusion in closed form); row is cache-hot
    const float s_rr = sim[(size_t)row * BN + row];
    const float l_rr = s_rr * INV_TAU;
    const float ex_rr_f = exp2f(fmaf(s_rr, K2F, -C2F));  // same fp as loop -> exact cancel
    const double ex_rr = (double)ex_rr_f;
    const float2 fr = __half22float2(code[row]);
    const bool rp = fr.x > 0.f, rrn = fr.x < 0.f, ru = fr.y > 0.5f;
    const float asr = fmaxf(fr.x, 0.f);
    const float rbr = fmaxf(-fr.x, 0.f);

    const double se_ex = fmax(Se - ex_rr, 1e-300);
    const double logZ = (double)COFF + log(se_ex);

    if (do_pu) {
      int P_tot = 0, RN_tot = 0; float A_tot = 0.f;
#pragma unroll
      for (int b = 0; b < NPB; ++b) {
        P_tot += hd->part_P[b]; RN_tot += hd->part_RN[b]; A_tot += hd->part_A[b];
      }
      const float pw_rr = pw[(size_t)row * BN + row];
      const int U_tot = BN - P_tot - RN_tot;
      const int cp  = P_tot  - (rp ? 1 : 0);
      const int crn = RN_tot - (rrn ? 1 : 0);
      const int cu  = U_tot  - (ru ? 1 : 0);
      const double Apos  = (double)A_tot - (double)asr;
      const double SaL   = (double)INV_TAU * Sa - (double)asr * (double)l_rr;
      const double sp_ex = Sp - (rp ? ex_rr : 0.0);
      const double sr_ex = Sr - (double)rbr * (double)pw_rr * ex_rr;
      const double su_ex = Su - (ru ? (double)pw_rr * ex_rr : 0.0);

      const double Lpos = (cp > 0) ? (-(SaL - logZ * Apos) / cp) : 0.0;
      const double Lrn  = (crn > 0) ? ((sr_ex / se_ex) / crn) : 0.0;
      const double EU = (su_ex / se_ex) / (cu > 0 ? cu : 1);
      const double EP = (sp_ex / se_ex) / (cp > 0 ? cp : 1);
      double pi = (double)pia[row];
      pi = pi < 1e-4 ? 1e-4 : (pi > 0.5 ? 0.5 : pi);
      const double deb = (EU - pi * EP) / (1.0 - pi + 1e-8);
      const double Lu = (cu > 0 && cp > 0) ? (deb > 0.0 ? deb : 0.0) : 0.0;
      loss_pu[row] = (float)(Lpos + Lrn + Lu);
    }
    if (w_inf != 0.0f) {
      const double logZf = (double)COFF + log(Se);   // full row LSE (self included)
      ir[row] = (float)(logZf - (double)l_rr);
    }
  }
}

// ---------------- col: infonce column LSE (gated) + slice partials + last-block combine ----
__launch_bounds__(256)
__global__ void col_kernel(const float* __restrict__ sim, Header* __restrict__ hd,
                           const float* __restrict__ loss_pu, const float* __restrict__ ir,
                           float* __restrict__ out) {
  const float w_inf = hd->w_inf, w_pu = hd->w_pu, w_prior = hd->w_prior;
  const int b = blockIdx.x;
  const int t = threadIdx.x;
  const int wid = t >> 6, lane = t & 63;

  // 1) column LSE for this block's 32 columns (only when epoch < PHASE2_END)
  double ic_sum = 0.0;   // accumulated in thread 0
  if (w_inf != 0.0f) {
    __shared__ float red[4][3];
    for (int k = 0; k < CPB; ++k) {
      const int col = b * CPB + k;
      float m = -3.0e38f, se = 0.f, diag = 0.f;
      for (int r = t; r < BN; r += 256) {
        const float l = sim[(size_t)r * BN + col] * INV_TAU;
        if (r == col) diag = l;
        if (l > m) { se *= __expf(m - l); m = l; }
        se += __expf(l - m);
      }
#pragma unroll
      for (int off = 32; off > 0; off >>= 1) {
        const float m2 = __shfl_xor(m, off), se2 = __shfl_xor(se, off);
        diag += __shfl_xor(diag, off);
        const float mn = fmaxf(m, m2);
        se = se * __expf(m - mn) + se2 * __expf(m2 - mn);
        m = mn;
      }
      if (lane == 0) { red[wid][0] = m; red[wid][1] = se; red[wid][2] = diag; }
      __syncthreads();
      if (t == 0) {
        float M = red[0][0], Se = red[0][1], Dg = red[0][2];
        for (int w = 1; w < 4; ++w) {
          const float mn = fmaxf(M, red[w][0]);
          Se = Se * __expf(M - mn) + red[w][1] * __expf(red[w][0] - mn);
          M = mn;
          Dg += red[w][2];
        }
        ic_sum += (double)M + log((double)Se) - (double)Dg;
      }
      __syncthreads();
    }
  }

  // 2) slice partials: rows [b*32, b*32+32) of loss_pu / ir
  float ps = 0.f, is_ = 0.f;
  if (t < CPB) {
    const int r = b * CPB + t;
    if (w_pu  != 0.0f) ps  = loss_pu[r];
    if (w_inf != 0.0f) is_ = ir[r];
  }
  if (t < 64) {
#pragma unroll
    for (int off = 32; off > 0; off >>= 1) {
      ps  += __shfl_xor(ps, off);
      is_ += __shfl_xor(is_, off);
    }
  }
  if (t == 0) {
    hd->pu_part[b] = ps;
    hd->ii_part[b] = is_ + (float)ic_sum;
  }
  __threadfence();
  __shared__ int last;
  if (t == 0) last = (atomicAdd(&hd->done, 1) == COL_BLKS - 1) ? 1 : 0;
  __syncthreads();
  if (!last) return;
  __threadfence();

  // 3) last block: final combine (deterministic regardless of which block is last)
  double pu = (double)hd->pu_part[t];
  double ii = (double)hd->ii_part[t];
  double pr = (t < NPB) ? (double)hd->part_prior[t] : 0.0;
#pragma unroll
  for (int off = 32; off > 0; off >>= 1) {
    pu += __shfl_xor(pu, off);
    ii += __shfl_xor(ii, off);
    pr += __shfl_xor(pr, off);
  }
  __shared__ double red2[4][3];
  if (lane == 0) { red2[wid][0] = pu; red2[wid][1] = ii; red2[wid][2] = pr; }
  __syncthreads();
  if (t == 0) {
    double PU = 0, II = 0, PR = 0;
#pragma unroll
    for (int w = 0; w < 4; ++w) { PU += red2[w][0]; II += red2[w][1]; PR += red2[w][2]; }
    double total = 0.0;
    if (w_pu    != 0.0f) total += (double)w_pu * (PU / (double)BN);
    if (w_inf   != 0.0f) total += (double)w_inf * (II / (2.0 * (double)BN));
    if (w_prior != 0.0f) total += (double)w_prior * 0.1 * (PR / (double)BN);
    out[0] = (float)total;
  }
}

extern "C" void kernel_launch(void* const* d_in, const int* in_sizes, int n_in,
                              void* d_out, int out_size, void* d_ws, size_t ws_size,
                              hipStream_t stream) {
  const float* sim    = (const float*)d_in[0];
  const int*   labels = (const int*)d_in[1];
  const float* alphas = (const float*)d_in[2];
  const float* betas  = (const float*)d_in[3];
  const float* pia    = (const float*)d_in[4];
  const float* pw     = (const float*)d_in[5];
  const float* pie    = (const float*)d_in[6];
  const int*   epoch  = (const int*)d_in[7];
  Header*  hd      = (Header*)d_ws;
  __half2* code    = (__half2*)((char*)d_ws + 4096);
  float*   loss_pu = (float*)((char*)d_ws + 40960);
  float*   ir      = (float*)((char*)d_ws + 73728);
  float*   out     = (float*)d_out;

  hipLaunchKernelGGL(prep_kernel, dim3(NPB), dim3(256), 0, stream,
                     labels, alphas, betas, pia, pie, epoch, hd, code);
  hipLaunchKernelGGL(row_kernel, dim3(BN), dim3(NT), 0, stream,
                     sim, pw, code, pia, hd, loss_pu, ir);
  hipLaunchKernelGGL(col_kernel, dim3(COL_BLKS), dim3(256), 0, stream,
                     sim, hd, loss_pu, ir, out);
}

// Round 12
// 108.491 us; speedup vs baseline: 1.1123x; 1.0992x over previous
//
#include <hip/hip_runtime.h>
#include <hip/hip_fp16.h>
#include <math.h>

#define BN 8192
#define NT 512
#define NW (NT / 64)
#define NGRP 4                 // 4 float4-groups/thread: 4*512*4 = 8192
#define INV_TAU (1.0f / 0.07f)
#define COFF 40.0f             // fixed softmax offset (replaces row max; exact math)
#define K2F 20.609929156f      // INV_TAU * log2(e)
#define C2F 57.707801636f      // COFF   * log2(e)
#define NPB 32                 // prep blocks
#define COL_BLKS 256
#define CPB (BN / COL_BLKS)    // 32 cols per col-block

// Plain-store workspace: no zero-init required anywhere.
struct Header {
  int   part_P[NPB];
  int   part_RN[NPB];
  float part_A[NPB];
  float part_prior[NPB];
  float w_inf, w_pu, w_prior;
};
// ws offsets (bytes): header @0 | code @4096 (32KB) | loss_pu @40960 (32KB)
//                     ir @73728 (32KB) | ic @106496 (32KB)

// ---------------- prep (32 blocks): per-block partial stats + packed selector code --------
// code[j] = half2 { v, q } : v = alpha (pos) | -beta (rn) | 0 ; q = 1 if unlabeled else 0
__global__ void prep_kernel(const int* __restrict__ labels, const float* __restrict__ alphas,
                            const float* __restrict__ betas, const float* __restrict__ pia,
                            const float* __restrict__ pie, const int* __restrict__ epoch_p,
                            Header* __restrict__ hd, __half2* __restrict__ code) {
  const int j = blockIdx.x * 256 + threadIdx.x;   // 32 * 256 = 8192
  const int l = labels[j];
  const bool isp = (l == 1), isrn = (l == -1);
  const float v = isp ? alphas[j] : (isrn ? -betas[j] : 0.f);
  const __half vh = __float2half(v);
  code[j] = __halves2half2(vh, __float2half((!isp && !isrn) ? 1.f : 0.f));
  int p = isp ? 1 : 0, rn = isrn ? 1 : 0;
  float a = isp ? __half2float(vh) : 0.f;         // A_tot from the SAME rounded alphas
  const float d = pia[j] - pie[j];
  float pr = d * d;
#pragma unroll
  for (int off = 32; off > 0; off >>= 1) {
    p  += __shfl_xor(p, off);
    rn += __shfl_xor(rn, off);
    a  += __shfl_xor(a, off);
    pr += __shfl_xor(pr, off);
  }
  __shared__ int sp_[4], srn_[4];
  __shared__ float sa_[4], spr_[4];
  const int wid = threadIdx.x >> 6;
  if ((threadIdx.x & 63) == 0) { sp_[wid] = p; srn_[wid] = rn; sa_[wid] = a; spr_[wid] = pr; }
  __syncthreads();
  if (threadIdx.x == 0) {
    int P = 0, RN = 0; float A = 0.f, PR = 0.f;
#pragma unroll
    for (int w = 0; w < 4; ++w) { P += sp_[w]; RN += srn_[w]; A += sa_[w]; PR += spr_[w]; }
    hd->part_P[blockIdx.x] = P;
    hd->part_RN[blockIdx.x] = RN;
    hd->part_A[blockIdx.x] = A;
    hd->part_prior[blockIdx.x] = PR;
    if (blockIdx.x == 0) {
      const int ep = epoch_p[0];
      float w_inf, w_pu, w_prior;
      if (ep < 5) { w_inf = 1.f; w_pu = 0.f; w_prior = 0.f; }
      else {
        const float puw = (ep >= 15) ? 1.f : (float)(ep - 5) / 10.f;
        w_inf = 1.f - puw; w_pu = puw; w_prior = (ep >= 15) ? 1.f : 0.f;
      }
      hd->w_inf = w_inf; hd->w_pu = w_pu; hd->w_prior = w_prior;
    }
  }
}

// ---------------- per-row PU loss + gated infonce row LSE ----------------
// Round-7 proven geometry: NT=512, 12 hoisted float4/thread (grouped), bounds (512,4).
__launch_bounds__(NT, 4)
__global__ void row_kernel(const float* __restrict__ sim, const float* __restrict__ pw,
                           const __half2* __restrict__ code, const float* __restrict__ pia,
                           const Header* __restrict__ hd, float* __restrict__ loss_pu,
                           float* __restrict__ ir) {
  const int row = blockIdx.x;
  const float w_pu = hd->w_pu, w_inf = hd->w_inf;
  if (w_pu == 0.0f && w_inf == 0.0f) return;
  const bool do_pu = (w_pu != 0.0f);

  const float4* __restrict__ sim4 = (const float4*)(sim + (size_t)row * BN);
  const float4* __restrict__ cd4  = (const float4*)code;
  const float4* __restrict__ pwp  = do_pu ? (const float4*)(pw + (size_t)row * BN) : sim4;

  // ---- hoisted loads: 12 float4 per thread (grouped order, r4/r7-proven) ----
  float4 s4[NGRP], w4[NGRP], c4[NGRP];
#pragma unroll
  for (int it = 0; it < NGRP; ++it) s4[it] = sim4[threadIdx.x + it * NT];
#pragma unroll
  for (int it = 0; it < NGRP; ++it) w4[it] = pwp[threadIdx.x + it * NT];
#pragma unroll
  for (int it = 0; it < NGRP; ++it) c4[it] = cd4[threadIdx.x + it * NT];

  float se = 0.f, sp = 0.f, srn = 0.f, su = 0.f, sas = 0.f;
#pragma unroll
  for (int it = 0; it < NGRP; ++it) {
    const float sv[4] = {s4[it].x, s4[it].y, s4[it].z, s4[it].w};
    const float wv[4] = {w4[it].x, w4[it].y, w4[it].z, w4[it].w};
    const float cf[4] = {c4[it].x, c4[it].y, c4[it].z, c4[it].w};
#pragma unroll
    for (int c = 0; c < 4; ++c) {
      const __half2 h = __builtin_bit_cast(__half2, cf[c]);
      const float2 f = __half22float2(h);     // f.x = v (+alpha/-beta/0), f.y = q (1 if u)
      const float s = sv[c];
      const float ex = exp2f(fmaf(s, K2F, -C2F));   // = exp(s/tau - COFF)
      se += ex;
      const float we = wv[c] * ex;
      sp += (f.x > 0.f) ? ex : 0.f;
      su  = fmaf(f.y, we, su);
      srn = fmaf(fmaxf(-f.x, 0.f), we, srn);
      sas = fmaf(fmaxf(f.x, 0.f), s, sas);
    }
  }

  const int wid = threadIdx.x >> 6;
  const int lane = threadIdx.x & 63;
#pragma unroll
  for (int off = 32; off > 0; off >>= 1) {
    se  += __shfl_xor(se, off);
    sp  += __shfl_xor(sp, off);
    srn += __shfl_xor(srn, off);
    su  += __shfl_xor(su, off);
    sas += __shfl_xor(sas, off);
  }
  __shared__ float red[NW][8];
  if (lane == 0) {
    red[wid][0] = se; red[wid][1] = sp; red[wid][2] = srn;
    red[wid][3] = su; red[wid][4] = sas;
  }
  __syncthreads();

  if (threadIdx.x == 0) {
    double Se = 0.0, Sp = 0.0, Sr = 0.0, Su = 0.0, Sa = 0.0;
#pragma unroll
    for (int w = 0; w < NW; ++w) {
      Se += (double)red[w][0]; Sp += (double)red[w][1]; Sr += (double)red[w][2];
      Su += (double)red[w][3]; Sa += (double)red[w][4];
    }
    // diagonal contributions (self-exclusion in closed form); row is cache-hot
    const float s_rr = sim[(size_t)row * BN + row];
    const float l_rr = s_rr * INV_TAU;
    const float ex_rr_f = exp2f(fmaf(s_rr, K2F, -C2F));  // same fp as loop -> exact cancel
    const double ex_rr = (double)ex_rr_f;
    const float2 fr = __half22float2(code[row]);
    const bool rp = fr.x > 0.f, rrn = fr.x < 0.f, ru = fr.y > 0.5f;
    const float asr = fmaxf(fr.x, 0.f);
    const float rbr = fmaxf(-fr.x, 0.f);

    const double se_ex = fmax(Se - ex_rr, 1e-300);
    const double logZ = (double)COFF + log(se_ex);

    if (do_pu) {
      int P_tot = 0, RN_tot = 0; float A_tot = 0.f;
#pragma unroll
      for (int b = 0; b < NPB; ++b) {
        P_tot += hd->part_P[b]; RN_tot += hd->part_RN[b]; A_tot += hd->part_A[b];
      }
      const float pw_rr = pw[(size_t)row * BN + row];
      const int U_tot = BN - P_tot - RN_tot;
      const int cp  = P_tot  - (rp ? 1 : 0);
      const int crn = RN_tot - (rrn ? 1 : 0);
      const int cu  = U_tot  - (ru ? 1 : 0);
      const double Apos  = (double)A_tot - (double)asr;
      const double SaL   = (double)INV_TAU * Sa - (double)asr * (double)l_rr;
      const double sp_ex = Sp - (rp ? ex_rr : 0.0);
      const double sr_ex = Sr - (double)rbr * (double)pw_rr * ex_rr;
      const double su_ex = Su - (ru ? (double)pw_rr * ex_rr : 0.0);

      const double Lpos = (cp > 0) ? (-(SaL - logZ * Apos) / cp) : 0.0;
      const double Lrn  = (crn > 0) ? ((sr_ex / se_ex) / crn) : 0.0;
      const double EU = (su_ex / se_ex) / (cu > 0 ? cu : 1);
      const double EP = (sp_ex / se_ex) / (cp > 0 ? cp : 1);
      double pi = (double)pia[row];
      pi = pi < 1e-4 ? 1e-4 : (pi > 0.5 ? 0.5 : pi);
      const double deb = (EU - pi * EP) / (1.0 - pi + 1e-8);
      const double Lu = (cu > 0 && cp > 0) ? (deb > 0.0 ? deb : 0.0) : 0.0;
      loss_pu[row] = (float)(Lpos + Lrn + Lu);
    }
    if (w_inf != 0.0f) {
      const double logZf = (double)COFF + log(Se);   // full row LSE (self included)
      ir[row] = (float)(logZf - (double)l_rr);
    }
  }
}

// ---------------- infonce column LSE (only active when epoch < PHASE2_END) ----------------
__launch_bounds__(256)
__global__ void col_kernel(const float* __restrict__ sim, const Header* __restrict__ hd,
                           float* __restrict__ ic) {
  if (hd->w_inf == 0.0f) return;
  for (int k = 0; k < CPB; ++k) {
    const int col = blockIdx.x * CPB + k;
    float m = -3.0e38f, se = 0.f, diag = 0.f;
    for (int r = threadIdx.x; r < BN; r += 256) {
      const float l = sim[(size_t)r * BN + col] * INV_TAU;
      if (r == col) diag = l;
      if (l > m) { se *= __expf(m - l); m = l; }
      se += __expf(l - m);
    }
#pragma unroll
    for (int off = 32; off > 0; off >>= 1) {
      const float m2 = __shfl_xor(m, off), se2 = __shfl_xor(se, off);
      diag += __shfl_xor(diag, off);
      const float mn = fmaxf(m, m2);
      se = se * __expf(m - mn) + se2 * __expf(m2 - mn);
      m = mn;
    }
    __shared__ float red[4][3];
    const int wid = threadIdx.x >> 6;
    const int lane = threadIdx.x & 63;
    if (lane == 0) { red[wid][0] = m; red[wid][1] = se; red[wid][2] = diag; }
    __syncthreads();
    if (threadIdx.x == 0) {
      float M = red[0][0], Se = red[0][1], Dg = red[0][2];
      for (int w = 1; w < 4; ++w) {
        const float mn = fmaxf(M, red[w][0]);
        Se = Se * __expf(M - mn) + red[w][1] * __expf(red[w][0] - mn);
        M = mn;
        Dg += red[w][2];
      }
      ic[col] = (float)((double)M + log((double)Se) - (double)Dg);
    }
    __syncthreads();
  }
}

// ---------------- final combine: reduce per-row losses (L2-resident) ----------------
__launch_bounds__(256)
__global__ void final_kernel(const Header* __restrict__ hd, const float* __restrict__ loss_pu,
                             const float* __restrict__ ir, const float* __restrict__ ic,
                             float* __restrict__ out) {
  const int t = threadIdx.x;  // 256
  const float w_inf = hd->w_inf, w_pu = hd->w_pu, w_prior = hd->w_prior;
  double pu = 0.0, irs = 0.0, ics = 0.0;
  if (w_pu != 0.0f)
    for (int j = t; j < BN; j += 256) pu += (double)loss_pu[j];
  if (w_inf != 0.0f)
    for (int j = t; j < BN; j += 256) { irs += (double)ir[j]; ics += (double)ic[j]; }
  double pr = (t < NPB) ? (double)hd->part_prior[t] : 0.0;
#pragma unroll
  for (int off = 32; off > 0; off >>= 1) {
    pu  += __shfl_xor(pu, off);
    irs += __shfl_xor(irs, off);
    ics += __shfl_xor(ics, off);
    pr  += __shfl_xor(pr, off);
  }
  __shared__ double red[4][4];
  const int wid = t >> 6, lane = t & 63;
  if (lane == 0) { red[wid][0] = pu; red[wid][1] = irs; red[wid][2] = ics; red[wid][3] = pr; }
  __syncthreads();
  if (t == 0) {
    double PU = 0, IR = 0, IC = 0, PR = 0;
#pragma unroll
    for (int w = 0; w < 4; ++w) { PU += red[w][0]; IR += red[w][1]; IC += red[w][2]; PR += red[w][3]; }
    double total = 0.0;
    if (w_pu != 0.0f)    total += (double)w_pu * (PU / (double)BN);
    if (w_inf != 0.0f)   total += (double)w_inf * ((IR + IC) / (2.0 * (double)BN));
    if (w_prior != 0.0f) total += (double)w_prior * 0.1 * (PR / (double)BN);
    out[0] = (float)total;
  }
}

extern "C" void kernel_launch(void* const* d_in, const int* in_sizes, int n_in,
                              void* d_out, int out_size, void* d_ws, size_t ws_size,
                              hipStream_t stream) {
  const float* sim    = (const float*)d_in[0];
  const int*   labels = (const int*)d_in[1];
  const float* alphas = (const float*)d_in[2];
  const float* betas  = (const float*)d_in[3];
  const float* pia    = (const float*)d_in[4];
  const float* pw     = (const float*)d_in[5];
  const float* pie    = (const float*)d_in[6];
  const int*   epoch  = (const int*)d_in[7];
  Header*  hd      = (Header*)d_ws;
  __half2* code    = (__half2*)((char*)d_ws + 4096);
  float*   loss_pu = (float*)((char*)d_ws + 40960);
  float*   ir      = (float*)((char*)d_ws + 73728);
  float*   ic      = (float*)((char*)d_ws + 106496);
  float*   out     = (float*)d_out;

  hipLaunchKernelGGL(prep_kernel, dim3(NPB), dim3(256), 0, stream,
                     labels, alphas, betas, pia, pie, epoch, hd, code);
  hipLaunchKernelGGL(row_kernel, dim3(BN), dim3(NT), 0, stream,
                     sim, pw, code, pia, hd, loss_pu, ir);
  hipLaunchKernelGGL(col_kernel, dim3(COL_BLKS), dim3(256), 0, stream, sim, hd, ic);
  hipLaunchKernelGGL(final_kernel, dim3(1), dim3(256), 0, stream, hd, loss_pu, ir, ic, out);
}

// Round 13
// 107.791 us; speedup vs baseline: 1.1195x; 1.0065x over previous
//
#include <hip/hip_runtime.h>
#include <hip/hip_fp16.h>
#include <math.h>

#define BN 8192
#define NT 512
#define NW (NT / 64)
#define NGRP 4                 // 4 float4-groups/thread: 4*512*4 = 8192
#define INV_TAU (1.0f / 0.07f)
#define COFF 40.0f             // fixed softmax offset (replaces row max; exact math)
#define K2F 20.609929156f      // INV_TAU * log2(e)
#define C2F 57.707801636f      // COFF   * log2(e)
#define NPB 32                 // prep blocks
#define COL_BLKS 256
#define CPB (BN / COL_BLKS)    // 32 cols per col-block

// Plain-store workspace: no zero-init required anywhere.
struct Header {
  int   part_P[NPB];
  int   part_RN[NPB];
  float part_A[NPB];
  float part_prior[NPB];
  float w_inf, w_pu, w_prior;
};
// ws offsets (bytes): header @0 | code @4096 (32KB) | loss_pu @40960 (32KB)
//                     ir @73728 (32KB) | ic @106496 (32KB)

// ---------------- prep (32 blocks): per-block partial stats + packed selector code --------
// code[j] = half2 { v, q } : v = alpha (pos) | -beta (rn) | 0 ; q = 1 if unlabeled else 0
__global__ void prep_kernel(const int* __restrict__ labels, const float* __restrict__ alphas,
                            const float* __restrict__ betas, const float* __restrict__ pia,
                            const float* __restrict__ pie, const int* __restrict__ epoch_p,
                            Header* __restrict__ hd, __half2* __restrict__ code) {
  const int j = blockIdx.x * 256 + threadIdx.x;   // 32 * 256 = 8192
  const int l = labels[j];
  const bool isp = (l == 1), isrn = (l == -1);
  const float v = isp ? alphas[j] : (isrn ? -betas[j] : 0.f);
  const __half vh = __float2half(v);
  code[j] = __halves2half2(vh, __float2half((!isp && !isrn) ? 1.f : 0.f));
  int p = isp ? 1 : 0, rn = isrn ? 1 : 0;
  float a = isp ? __half2float(vh) : 0.f;         // A_tot from the SAME rounded alphas
  const float d = pia[j] - pie[j];
  float pr = d * d;
#pragma unroll
  for (int off = 32; off > 0; off >>= 1) {
    p  += __shfl_xor(p, off);
    rn += __shfl_xor(rn, off);
    a  += __shfl_xor(a, off);
    pr += __shfl_xor(pr, off);
  }
  __shared__ int sp_[4], srn_[4];
  __shared__ float sa_[4], spr_[4];
  const int wid = threadIdx.x >> 6;
  if ((threadIdx.x & 63) == 0) { sp_[wid] = p; srn_[wid] = rn; sa_[wid] = a; spr_[wid] = pr; }
  __syncthreads();
  if (threadIdx.x == 0) {
    int P = 0, RN = 0; float A = 0.f, PR = 0.f;
#pragma unroll
    for (int w = 0; w < 4; ++w) { P += sp_[w]; RN += srn_[w]; A += sa_[w]; PR += spr_[w]; }
    hd->part_P[blockIdx.x] = P;
    hd->part_RN[blockIdx.x] = RN;
    hd->part_A[blockIdx.x] = A;
    hd->part_prior[blockIdx.x] = PR;
    if (blockIdx.x == 0) {
      const int ep = epoch_p[0];
      float w_inf, w_pu, w_prior;
      if (ep < 5) { w_inf = 1.f; w_pu = 0.f; w_prior = 0.f; }
      else {
        const float puw = (ep >= 15) ? 1.f : (float)(ep - 5) / 10.f;
        w_inf = 1.f - puw; w_pu = puw; w_prior = (ep >= 15) ? 1.f : 0.f;
      }
      hd->w_inf = w_inf; hd->w_pu = w_pu; hd->w_prior = w_prior;
    }
  }
}

// ---------------- per-row PU loss + gated infonce row LSE ----------------
// r12 geometry, but __launch_bounds__(512,8): 8 waves/EU = 32 waves/CU (was 16).
// VGPR cap 64 vs current use 32 -> codegen unchanged, occupancy doubles.
__launch_bounds__(NT, 8)
__global__ void row_kernel(const float* __restrict__ sim, const float* __restrict__ pw,
                           const __half2* __restrict__ code, const float* __restrict__ pia,
                           const Header* __restrict__ hd, float* __restrict__ loss_pu,
                           float* __restrict__ ir) {
  const int row = blockIdx.x;
  const float w_pu = hd->w_pu, w_inf = hd->w_inf;
  if (w_pu == 0.0f && w_inf == 0.0f) return;
  const bool do_pu = (w_pu != 0.0f);

  const float4* __restrict__ sim4 = (const float4*)(sim + (size_t)row * BN);
  const float4* __restrict__ cd4  = (const float4*)code;
  const float4* __restrict__ pwp  = do_pu ? (const float4*)(pw + (size_t)row * BN) : sim4;

  // ---- hoisted loads: 12 float4 per thread (grouped order, r4/r7-proven) ----
  float4 s4[NGRP], w4[NGRP], c4[NGRP];
#pragma unroll
  for (int it = 0; it < NGRP; ++it) s4[it] = sim4[threadIdx.x + it * NT];
#pragma unroll
  for (int it = 0; it < NGRP; ++it) w4[it] = pwp[threadIdx.x + it * NT];
#pragma unroll
  for (int it = 0; it < NGRP; ++it) c4[it] = cd4[threadIdx.x + it * NT];

  float se = 0.f, sp = 0.f, srn = 0.f, su = 0.f, sas = 0.f;
#pragma unroll
  for (int it = 0; it < NGRP; ++it) {
    const float sv[4] = {s4[it].x, s4[it].y, s4[it].z, s4[it].w};
    const float wv[4] = {w4[it].x, w4[it].y, w4[it].z, w4[it].w};
    const float cf[4] = {c4[it].x, c4[it].y, c4[it].z, c4[it].w};
#pragma unroll
    for (int c = 0; c < 4; ++c) {
      const __half2 h = __builtin_bit_cast(__half2, cf[c]);
      const float2 f = __half22float2(h);     // f.x = v (+alpha/-beta/0), f.y = q (1 if u)
      const float s = sv[c];
      const float ex = exp2f(fmaf(s, K2F, -C2F));   // = exp(s/tau - COFF)
      se += ex;
      const float we = wv[c] * ex;
      sp += (f.x > 0.f) ? ex : 0.f;
      su  = fmaf(f.y, we, su);
      srn = fmaf(fmaxf(-f.x, 0.f), we, srn);
      sas = fmaf(fmaxf(f.x, 0.f), s, sas);
    }
  }

  const int wid = threadIdx.x >> 6;
  const int lane = threadIdx.x & 63;
#pragma unroll
  for (int off = 32; off > 0; off >>= 1) {
    se  += __shfl_xor(se, off);
    sp  += __shfl_xor(sp, off);
    srn += __shfl_xor(srn, off);
    su  += __shfl_xor(su, off);
    sas += __shfl_xor(sas, off);
  }
  __shared__ float red[NW][8];
  if (lane == 0) {
    red[wid][0] = se; red[wid][1] = sp; red[wid][2] = srn;
    red[wid][3] = su; red[wid][4] = sas;
  }
  __syncthreads();

  if (threadIdx.x == 0) {
    double Se = 0.0, Sp = 0.0, Sr = 0.0, Su = 0.0, Sa = 0.0;
#pragma unroll
    for (int w = 0; w < NW; ++w) {
      Se += (double)red[w][0]; Sp += (double)red[w][1]; Sr += (double)red[w][2];
      Su += (double)red[w][3]; Sa += (double)red[w][4];
    }
    // diagonal contributions (self-exclusion in closed form); row is cache-hot
    const float s_rr = sim[(size_t)row * BN + row];
    const float l_rr = s_rr * INV_TAU;
    const float ex_rr_f = exp2f(fmaf(s_rr, K2F, -C2F));  // same fp as loop -> exact cancel
    const double ex_rr = (double)ex_rr_f;
    const float2 fr = __half22float2(code[row]);
    const bool rp = fr.x > 0.f, rrn = fr.x < 0.f, ru = fr.y > 0.5f;
    const float asr = fmaxf(fr.x, 0.f);
    const float rbr = fmaxf(-fr.x, 0.f);

    const double se_ex = fmax(Se - ex_rr, 1e-300);
    const double logZ = (double)COFF + log(se_ex);

    if (do_pu) {
      int P_tot = 0, RN_tot = 0; float A_tot = 0.f;
#pragma unroll
      for (int b = 0; b < NPB; ++b) {
        P_tot += hd->part_P[b]; RN_tot += hd->part_RN[b]; A_tot += hd->part_A[b];
      }
      const float pw_rr = pw[(size_t)row * BN + row];
      const int U_tot = BN - P_tot - RN_tot;
      const int cp  = P_tot  - (rp ? 1 : 0);
      const int crn = RN_tot - (rrn ? 1 : 0);
      const int cu  = U_tot  - (ru ? 1 : 0);
      const double Apos  = (double)A_tot - (double)asr;
      const double SaL   = (double)INV_TAU * Sa - (double)asr * (double)l_rr;
      const double sp_ex = Sp - (rp ? ex_rr : 0.0);
      const double sr_ex = Sr - (double)rbr * (double)pw_rr * ex_rr;
      const double su_ex = Su - (ru ? (double)pw_rr * ex_rr : 0.0);

      const double Lpos = (cp > 0) ? (-(SaL - logZ * Apos) / cp) : 0.0;
      const double Lrn  = (crn > 0) ? ((sr_ex / se_ex) / crn) : 0.0;
      const double EU = (su_ex / se_ex) / (cu > 0 ? cu : 1);
      const double EP = (sp_ex / se_ex) / (cp > 0 ? cp : 1);
      double pi = (double)pia[row];
      pi = pi < 1e-4 ? 1e-4 : (pi > 0.5 ? 0.5 : pi);
      const double deb = (EU - pi * EP) / (1.0 - pi + 1e-8);
      const double Lu = (cu > 0 && cp > 0) ? (deb > 0.0 ? deb : 0.0) : 0.0;
      loss_pu[row] = (float)(Lpos + Lrn + Lu);
    }
    if (w_inf != 0.0f) {
      const double logZf = (double)COFF + log(Se);   // full row LSE (self included)
      ir[row] = (float)(logZf - (double)l_rr);
    }
  }
}

// ---------------- infonce column LSE (only active when epoch < PHASE2_END) ----------------
__launch_bounds__(256)
__global__ void col_kernel(const float* __restrict__ sim, const Header* __restrict__ hd,
                           float* __restrict__ ic) {
  if (hd->w_inf == 0.0f) return;
  for (int k = 0; k < CPB; ++k) {
    const int col = blockIdx.x * CPB + k;
    float m = -3.0e38f, se = 0.f, diag = 0.f;
    for (int r = threadIdx.x; r < BN; r += 256) {
      const float l = sim[(size_t)r * BN + col] * INV_TAU;
      if (r == col) diag = l;
      if (l > m) { se *= __expf(m - l); m = l; }
      se += __expf(l - m);
    }
#pragma unroll
    for (int off = 32; off > 0; off >>= 1) {
      const float m2 = __shfl_xor(m, off), se2 = __shfl_xor(se, off);
      diag += __shfl_xor(diag, off);
      const float mn = fmaxf(m, m2);
      se = se * __expf(m - mn) + se2 * __expf(m2 - mn);
      m = mn;
    }
    __shared__ float red[4][3];
    const int wid = threadIdx.x >> 6;
    const int lane = threadIdx.x & 63;
    if (lane == 0) { red[wid][0] = m; red[wid][1] = se; red[wid][2] = diag; }
    __syncthreads();
    if (threadIdx.x == 0) {
      float M = red[0][0], Se = red[0][1], Dg = red[0][2];
      for (int w = 1; w < 4; ++w) {
        const float mn = fmaxf(M, red[w][0]);
        Se = Se * __expf(M - mn) + red[w][1] * __expf(red[w][0] - mn);
        M = mn;
        Dg += red[w][2];
      }
      ic[col] = (float)((double)M + log((double)Se) - (double)Dg);
    }
    __syncthreads();
  }
}

// ---------------- final combine: reduce per-row losses (L2-resident) ----------------
__launch_bounds__(256)
__global__ void final_kernel(const Header* __restrict__ hd, const float* __restrict__ loss_pu,
                             const float* __restrict__ ir, const float* __restrict__ ic,
                             float* __restrict__ out) {
  const int t = threadIdx.x;  // 256
  const float w_inf = hd->w_inf, w_pu = hd->w_pu, w_prior = hd->w_prior;
  double pu = 0.0, irs = 0.0, ics = 0.0;
  if (w_pu != 0.0f)
    for (int j = t; j < BN; j += 256) pu += (double)loss_pu[j];
  if (w_inf != 0.0f)
    for (int j = t; j < BN; j += 256) { irs += (double)ir[j]; ics += (double)ic[j]; }
  double pr = (t < NPB) ? (double)hd->part_prior[t] : 0.0;
#pragma unroll
  for (int off = 32; off > 0; off >>= 1) {
    pu  += __shfl_xor(pu, off);
    irs += __shfl_xor(irs, off);
    ics += __shfl_xor(ics, off);
    pr  += __shfl_xor(pr, off);
  }
  __shared__ double red[4][4];
  const int wid = t >> 6, lane = t & 63;
  if (lane == 0) { red[wid][0] = pu; red[wid][1] = irs; red[wid][2] = ics; red[wid][3] = pr; }
  __syncthreads();
  if (t == 0) {
    double PU = 0, IR = 0, IC = 0, PR = 0;
#pragma unroll
    for (int w = 0; w < 4; ++w) { PU += red[w][0]; IR += red[w][1]; IC += red[w][2]; PR += red[w][3]; }
    double total = 0.0;
    if (w_pu != 0.0f)    total += (double)w_pu * (PU / (double)BN);
    if (w_inf != 0.0f)   total += (double)w_inf * ((IR + IC) / (2.0 * (double)BN));
    if (w_prior != 0.0f) total += (double)w_prior * 0.1 * (PR / (double)BN);
    out[0] = (float)total;
  }
}

extern "C" void kernel_launch(void* const* d_in, const int* in_sizes, int n_in,
                              void* d_out, int out_size, void* d_ws, size_t ws_size,
                              hipStream_t stream) {
  const float* sim    = (const float*)d_in[0];
  const int*   labels = (const int*)d_in[1];
  const float* alphas = (const float*)d_in[2];
  const float* betas  = (const float*)d_in[3];
  const float* pia    = (const float*)d_in[4];
  const float* pw     = (const float*)d_in[5];
  const float* pie    = (const float*)d_in[6];
  const int*   epoch  = (const int*)d_in[7];
  Header*  hd      = (Header*)d_ws;
  __half2* code    = (__half2*)((char*)d_ws + 4096);
  float*   loss_pu = (float*)((char*)d_ws + 40960);
  float*   ir      = (float*)((char*)d_ws + 73728);
  float*   ic      = (float*)((char*)d_ws + 106496);
  float*   out     = (float*)d_out;

  hipLaunchKernelGGL(prep_kernel, dim3(NPB), dim3(256), 0, stream,
                     labels, alphas, betas, pia, pie, epoch, hd, code);
  hipLaunchKernelGGL(row_kernel, dim3(BN), dim3(NT), 0, stream,
                     sim, pw, code, pia, hd, loss_pu, ir);
  hipLaunchKernelGGL(col_kernel, dim3(COL_BLKS), dim3(256), 0, stream, sim, hd, ic);
  hipLaunchKernelGGL(final_kernel, dim3(1), dim3(256), 0, stream, hd, loss_pu, ir, ic, out);
}